// Round 10
// baseline (164.619 us; speedup 1.0000x reference)
//
#include <hip/hip_runtime.h>
#include <stdint.h>

#define M_DIM 1024
#define K_DIM 4096
#define N_DIM 11008
#define NPACK 1376
#define NGROUPS 32
#define K8 (K_DIM / 8)      // 512

#define BM 128              // 4 mf-fragments x 32 rows
#define BN 128              // 4 waves x 32 cols
#define BK 64
#define NT (K_DIM / BK)     // 64

typedef __attribute__((ext_vector_type(16))) float f32x16;
typedef __attribute__((ext_vector_type(4))) float f32x4;
typedef __attribute__((ext_vector_type(8))) _Float16 f16x8;
typedef __attribute__((ext_vector_type(2))) _Float16 h2;

static __device__ __forceinline__ unsigned swz(unsigned r) {
  return (r ^ (r >> 3)) & 7u;
}

// ---------- prepass 1: x fp32 -> fp16 packed in MFMA-fragment order ----------
// XP[((rg*K8 + k8)*32 + l31)*8 + i] = fp16(X[rg*32 + l31][k8*8 + i])
// (fp32->fp16 exact: x was originally fp16). Reads coalesced, writes scattered 16B.
__global__ __launch_bounds__(256)
void conv_pack(const float* __restrict__ X, unsigned short* __restrict__ XP) {
  const int idx = blockIdx.x * 256 + threadIdx.x;   // M*K8 = 524288 threads
  const int row = idx >> 9;                          // /K8
  const int k8  = idx & (K8 - 1);
  const float* src = X + (size_t)row * K_DIM + k8 * 8;
  const float4 a = *(const float4*)src;
  const float4 b = *(const float4*)(src + 4);
  uint4 o;
  o.x = __builtin_bit_cast(unsigned, __builtin_amdgcn_cvt_pkrtz(a.x, a.y));
  o.y = __builtin_bit_cast(unsigned, __builtin_amdgcn_cvt_pkrtz(a.z, a.w));
  o.z = __builtin_bit_cast(unsigned, __builtin_amdgcn_cvt_pkrtz(b.x, b.y));
  o.w = __builtin_bit_cast(unsigned, __builtin_amdgcn_cvt_pkrtz(b.z, b.w));
  const size_t off = (((size_t)(row >> 5) * K8 + k8) * 32 + (row & 31)) * 8;
  *(uint4*)(XP + off) = o;
}

// ---------- prepass 2: repack qweight nibbles K-major per column ----------
__global__ __launch_bounds__(256)
void repack_qw(const int* __restrict__ QW, unsigned* __restrict__ QWR) {
  const int idx = blockIdx.x * 256 + threadIdx.x;
  const int p  = idx % NPACK;
  const int k8 = idx / NPACK;
  unsigned a[8];
  #pragma unroll
  for (int i = 0; i < 8; ++i)
    a[i] = (unsigned)QW[(size_t)(k8 * 8 + i) * NPACK + p];
  #pragma unroll
  for (int i = 0; i < 8; i += 2) {
    unsigned t = ((a[i] >> 4) ^ a[i + 1]) & 0x0F0F0F0Fu;
    a[i + 1] ^= t;  a[i] ^= t << 4;
  }
  #pragma unroll
  for (int g = 0; g < 8; g += 4)
    #pragma unroll
    for (int i = 0; i < 2; ++i) {
      unsigned t = ((a[g + i] >> 8) ^ a[g + i + 2]) & 0x00FF00FFu;
      a[g + i + 2] ^= t;  a[g + i] ^= t << 8;
    }
  #pragma unroll
  for (int i = 0; i < 4; ++i) {
    unsigned t = ((a[i] >> 16) ^ a[i + 4]) & 0x0000FFFFu;
    a[i + 4] ^= t;  a[i] ^= t << 16;
  }
  const int REV[8] = {0, 4, 1, 5, 2, 6, 3, 7};
  #pragma unroll
  for (int j = 0; j < 8; ++j)
    QWR[(size_t)k8 * N_DIM + 8 * p + j] = a[REV[j]];
}

// ---------- main: LDS-free register streaming, mf=4, 32x32x16 MFMA ----------
__global__ __launch_bounds__(256, 2)
void awq_gemm_rs(const unsigned short* __restrict__ XP,
                 const unsigned* __restrict__ QWR,
                 const int* __restrict__ QZ,
                 const float* __restrict__ S,
                 const float* __restrict__ BIAS,
                 float* __restrict__ OUT)
{
  const int tid  = threadIdx.x;
  const int lane = tid & 63;
  const int wcol = tid >> 6;      // 0..3
  const int l31  = lane & 31;
  const int hi   = lane >> 5;

  const int by  = blockIdx.y;               // 0..7
  const int n0  = blockIdx.x * BN;          // 0..85 * 128
  const int col = n0 + wcol * 32 + l31;

  const int jz   = col & 7;
  const int sh_z = (((jz >> 1) | ((jz & 1) << 2)) << 2);

  // A fragment pointers: frag(rg = by*4+mf, k8 = t*8 + ks*2 + hi) at
  // XP + ((rg*K8 + k8)*32 + l31)*8. Within a tile, ks offset = ks*1024B (imm).
  const unsigned short* acur0 = XP + (((size_t)(by * 4 + 0) * K8 + hi) * 32 + l31) * 8;
  const unsigned short* acur1 = XP + (((size_t)(by * 4 + 1) * K8 + hi) * 32 + l31) * 8;
  const unsigned short* acur2 = XP + (((size_t)(by * 4 + 2) * K8 + hi) * 32 + l31) * 8;
  const unsigned short* acur3 = XP + (((size_t)(by * 4 + 3) * K8 + hi) * 32 + l31) * 8;
  // per-tile advance: 8 k8-steps * 32 lanes * 8 halves = 2048 shorts

  const unsigned* bcur = QWR + (size_t)hi * N_DIM + col;
  // per-tile advance: 8 * N_DIM dwords

  f32x16 acc0 = (f32x16)(0.f), acc1 = (f32x16)(0.f);
  f32x16 acc2 = (f32x16)(0.f), acc3 = (f32x16)(0.f);

  unsigned zz, ss;
  unsigned qn; float sn;

  auto prepLoad = [&](int grp) {
    qn = (unsigned)QZ[grp * NPACK + (col >> 3)];
    sn = S[(size_t)grp * N_DIM + col];
  };
  auto prepCalc = [&]() {
    const unsigned z = (qn >> sh_z) & 15u;
    zz = z * 0x10001u + 0x64006400u;
    ss = __builtin_bit_cast(unsigned, __builtin_amdgcn_cvt_pkrtz(sn, sn));
  };

  f16x8 afA[4][4], afB[4][4];     // [mf][ks], static indexing only
  unsigned bqA[4], bqB[4];

  auto loadA = [&](f16x8 (*dst)[4]) {
    #pragma unroll
    for (int ks = 0; ks < 4; ++ks) {
      dst[0][ks] = *(const f16x8*)(acur0 + ks * 512);
      dst[1][ks] = *(const f16x8*)(acur1 + ks * 512);
      dst[2][ks] = *(const f16x8*)(acur2 + ks * 512);
      dst[3][ks] = *(const f16x8*)(acur3 + ks * 512);
    }
    acur0 += 2048; acur1 += 2048; acur2 += 2048; acur3 += 2048;
  };
  auto loadB = [&](unsigned* dst) {
    #pragma unroll
    for (int ks = 0; ks < 4; ++ks)
      dst[ks] = bcur[(size_t)(ks * 2) * N_DIM];
    bcur += (size_t)8 * N_DIM;
  };

  auto compute = [&](const f16x8 (*af)[4], const unsigned* bq) {
    #pragma unroll
    for (int ks = 0; ks < 4; ++ks) {
      const unsigned w = bq[ks];
      const unsigned e = w & 0x0F0F0F0Fu;
      const unsigned o = (w >> 4) & 0x0F0F0F0Fu;
      union { unsigned u[4]; f16x8 v; } bf;
      #pragma unroll
      for (int q = 0; q < 4; ++q) {
        const unsigned sel = 0x0C000C00u | (unsigned)q | ((unsigned)(4 + q) << 16);
        const unsigned hv  = __builtin_amdgcn_perm(o, e, sel) | 0x64006400u;
        const h2 wv = (__builtin_bit_cast(h2, hv) - __builtin_bit_cast(h2, zz)) *
                      __builtin_bit_cast(h2, ss);
        bf.u[q] = __builtin_bit_cast(unsigned, wv);
      }
      acc0 = __builtin_amdgcn_mfma_f32_32x32x16_f16(af[0][ks], bf.v, acc0, 0, 0, 0);
      acc1 = __builtin_amdgcn_mfma_f32_32x32x16_f16(af[1][ks], bf.v, acc1, 0, 0, 0);
      acc2 = __builtin_amdgcn_mfma_f32_32x32x16_f16(af[2][ks], bf.v, acc2, 0, 0, 0);
      acc3 = __builtin_amdgcn_mfma_f32_32x32x16_f16(af[3][ks], bf.v, acc3, 0, 0, 0);
    }
  };

  // ---------------- prologue ----------------
  prepLoad(0); prepCalc();
  loadA(afA); loadB(bqA);

  // ---------------- main loop: 32 iters x 2 tiles, no barriers ----------------
  for (int I = 0; I < 32; ++I) {
    // even tile 2I: prefetch 2I+1, compute on A-buf
    loadA(afB); loadB(bqB);
    compute(afA, bqA);
    // odd tile 2I+1: prefetch 2I+2, compute on B-buf
    if (I < 31) {
      loadA(afA); loadB(bqA);
      prepLoad(I + 1);
    }
    compute(afB, bqB);              // group-I constants
    if (I < 31) prepCalc();
  }

  // ---------------- epilogue ----------------
  // C/D 32x32 (m74/m101): col = lane&31, row = (reg&3) + 8*(reg>>2) + 4*(lane>>5)
  const float bz = BIAS[col];
  const f32x16* accs[4] = {&acc0, &acc1, &acc2, &acc3};
  #pragma unroll
  for (int mf = 0; mf < 4; ++mf) {
    const int rbase = by * BM + mf * 32 + 4 * hi;
    #pragma unroll
    for (int r = 0; r < 16; ++r) {
      const int row = rbase + (r & 3) + 8 * (r >> 2);
      OUT[(size_t)row * N_DIM + col] = (*accs[mf])[r] + bz;
    }
  }
}

// ---------------- fallback (round-5 structure, fp32 x, no/small ws) ----------------
__global__ __launch_bounds__(512, 2)
void awq_gemm_fb(const float* __restrict__ XF,
                 const int* __restrict__ QW,
                 const int* __restrict__ QZ,
                 const float* __restrict__ S,
                 const float* __restrict__ BIAS,
                 float* __restrict__ OUT)
{
  __shared__ unsigned short Al[2][256 * 64];
  __shared__ unsigned short Bl[2][256 * 64];

  const int tid = threadIdx.x, lane = tid & 63, wid = tid >> 6;
  const int wr = wid >> 2, wc = wid & 3, l15 = lane & 15, l4 = lane >> 4;
  const int row0 = blockIdx.y * 256, n0 = blockIdx.x * 256, p0 = n0 >> 3;
  const int dq_p = tid & 31, dq_k = (tid >> 5) << 2;

  f32x4 acc[8][4];
  #pragma unroll
  for (int i = 0; i < 8; ++i)
    #pragma unroll
    for (int j = 0; j < 4; ++j) acc[i][j] = (f32x4){0.f, 0.f, 0.f, 0.f};

  const int SH[8] = {0, 16, 4, 20, 8, 24, 12, 28};
  unsigned zz[8], ssv[8];

  auto stageA = [&](int buf, int k0) {
    #pragma unroll
    for (int i = 0; i < 4; ++i) {
      const int g = i * 512 + tid;
      const unsigned r = (unsigned)(g >> 3), c = (unsigned)(g & 7);
      const float* src = XF + (size_t)(row0 + r) * K_DIM + k0 + (c << 3);
      const float4 v0 = *(const float4*)src;
      const float4 v1 = *(const float4*)(src + 4);
      uint4 o;
      o.x = __builtin_bit_cast(unsigned, __builtin_amdgcn_cvt_pkrtz(v0.x, v0.y));
      o.y = __builtin_bit_cast(unsigned, __builtin_amdgcn_cvt_pkrtz(v0.z, v0.w));
      o.z = __builtin_bit_cast(unsigned, __builtin_amdgcn_cvt_pkrtz(v1.x, v1.y));
      o.w = __builtin_bit_cast(unsigned, __builtin_amdgcn_cvt_pkrtz(v1.z, v1.w));
      *(uint4*)((char*)&Al[buf][0] + r * 128 + ((c ^ swz(r)) << 4)) = o;
    }
  };
  auto prepGroup = [&](int grp) {
    const unsigned qzv = (unsigned)QZ[grp * NPACK + p0 + dq_p];
    const float* sp = S + (size_t)grp * N_DIM + n0 + dq_p * 8;
    const float4 sv0 = *(const float4*)sp;
    const float4 sv1 = *(const float4*)(sp + 4);
    const float svf[8] = {sv0.x, sv0.y, sv0.z, sv0.w, sv1.x, sv1.y, sv1.z, sv1.w};
    #pragma unroll
    for (int j = 0; j < 8; ++j) {
      const unsigned z = (qzv >> SH[j]) & 15u;
      zz[j] = z * 0x10001u + 0x64006400u;
      ssv[j] = __builtin_bit_cast(unsigned, __builtin_amdgcn_cvt_pkrtz(svf[j], svf[j]));
    }
  };
  unsigned qwc[4], qwn[4];
  auto loadQW = [&](unsigned* dst, int k0) {
    #pragma unroll
    for (int i = 0; i < 4; ++i)
      dst[i] = (unsigned)QW[(size_t)(k0 + dq_k + i) * NPACK + p0 + dq_p];
  };
  auto deqB = [&](int buf, const unsigned* qw) {
    #pragma unroll
    for (int j = 0; j < 8; ++j) {
      const int sh = SH[j];
      const unsigned q01 = ((qw[0] >> sh) & 15u) | (((qw[1] >> sh) & 15u) << 16) | 0x64006400u;
      const unsigned q23 = ((qw[2] >> sh) & 15u) | (((qw[3] >> sh) & 15u) << 16) | 0x64006400u;
      const h2 w01 = (__builtin_bit_cast(h2, q01) - __builtin_bit_cast(h2, zz[j])) *
                     __builtin_bit_cast(h2, ssv[j]);
      const h2 w23 = (__builtin_bit_cast(h2, q23) - __builtin_bit_cast(h2, zz[j])) *
                     __builtin_bit_cast(h2, ssv[j]);
      uint2 wb;
      wb.x = __builtin_bit_cast(unsigned, w01);
      wb.y = __builtin_bit_cast(unsigned, w23);
      const unsigned nn = dq_p * 8 + j;
      *(uint2*)((char*)&Bl[buf][0] + nn * 128 + ((dq_k * 2) ^ (swz(nn) << 4))) = wb;
    }
  };

  stageA(0, 0); prepGroup(0); loadQW(qwc, 0); deqB(0, qwc); loadQW(qwn, BK);
  __syncthreads();
  int cur = 0;
  for (int t = 0; t < NT; ++t) {
    if (t + 1 < NT) {
      const int kn = (t + 1) * BK;
      stageA(cur ^ 1, kn);
      if (((t + 1) & 1) == 0) prepGroup((t + 1) >> 1);
      deqB(cur ^ 1, qwn);
      if (t + 2 < NT) loadQW(qwn, kn + BK);
    }
    const char* Ac = (const char*)&Al[cur][0];
    const char* Bc = (const char*)&Bl[cur][0];
    #pragma unroll
    for (int kk = 0; kk < 2; ++kk) {
      f16x8 afv[8], bfv[4];
      #pragma unroll
      for (int m = 0; m < 8; ++m) {
        const unsigned r = (unsigned)(wr * 128 + m * 16 + l15);
        afv[m] = *(const f16x8*)(Ac + r * 128 + (((unsigned)(kk * 4 + l4) ^ swz(r)) << 4));
      }
      #pragma unroll
      for (int n = 0; n < 4; ++n) {
        const unsigned r = (unsigned)(wc * 64 + n * 16 + l15);
        bfv[n] = *(const f16x8*)(Bc + r * 128 + (((unsigned)(kk * 4 + l4) ^ swz(r)) << 4));
      }
      #pragma unroll
      for (int m = 0; m < 8; ++m)
        #pragma unroll
        for (int n = 0; n < 4; ++n)
          acc[m][n] = __builtin_amdgcn_mfma_f32_16x16x32_f16(afv[m], bfv[n], acc[m][n], 0, 0, 0);
    }
    __syncthreads();
    cur ^= 1;
  }
  #pragma unroll
  for (int n = 0; n < 4; ++n) {
    const int c2 = n0 + wc * 64 + n * 16 + l15;
    const float bz = BIAS[c2];
    #pragma unroll
    for (int m = 0; m < 8; ++m) {
      const int rbase = row0 + wr * 128 + m * 16 + l4 * 4;
      #pragma unroll
      for (int r = 0; r < 4; ++r)
        OUT[(size_t)(rbase + r) * N_DIM + c2] = acc[m][n][r] + bz;
    }
  }
}

extern "C" void kernel_launch(void* const* d_in, const int* in_sizes, int n_in,
                              void* d_out, int out_size, void* d_ws, size_t ws_size,
                              hipStream_t stream) {
  const float* x = nullptr; const int* qw = nullptr; const int* qz = nullptr;
  const float* s = nullptr; const float* b = nullptr;
  for (int i = 0; i < n_in; ++i) {
    switch (in_sizes[i]) {
      case M_DIM * K_DIM:   x  = (const float*)d_in[i]; break;
      case K_DIM * NPACK:   qw = (const int*)d_in[i];   break;
      case NGROUPS * NPACK: qz = (const int*)d_in[i];   break;
      case NGROUPS * N_DIM: s  = (const float*)d_in[i]; break;
      case N_DIM:           b  = (const float*)d_in[i]; break;
    }
  }
  float* out = (float*)d_out;

  const size_t xp_bytes  = (size_t)M_DIM * K_DIM * 2;          // 8 MiB
  const size_t qwr_bytes = (size_t)K8 * N_DIM * 4;             // 22.5 MiB
  const int repack_blocks = (NPACK * K8) / 256;                // 2752 exact

  if (ws_size >= xp_bytes + qwr_bytes) {
    unsigned short* xp = (unsigned short*)d_ws;
    unsigned* qwr = (unsigned*)((char*)d_ws + xp_bytes);
    conv_pack<<<(M_DIM * K8) / 256, 256, 0, stream>>>(x, xp);
    repack_qw<<<repack_blocks, 256, 0, stream>>>(qw, qwr);
    awq_gemm_rs<<<dim3(N_DIM / BN, M_DIM / BM), dim3(256), 0, stream>>>(
        xp, qwr, qz, s, b, out);
  } else {
    awq_gemm_fb<<<dim3(N_DIM / 256, M_DIM / 256), dim3(512), 0, stream>>>(
        x, qw, qz, s, b, out);
  }
}

// Round 11
// 125.867 us; speedup vs baseline: 1.3079x; 1.3079x over previous
//
#include <hip/hip_runtime.h>
#include <stdint.h>

#define M_DIM 1024
#define K_DIM 4096
#define N_DIM 11008
#define NPACK 1376
#define NGROUPS 32
#define K8 (K_DIM / 8)      // 512

#define BM 128
#define BN 128
#define BK 64
#define NT (K_DIM / BK)     // 64
#define ATILE (BM * BK)     // 8192 shorts = 16 KiB

typedef __attribute__((ext_vector_type(16))) float f32x16;
typedef __attribute__((ext_vector_type(4))) float f32x4;
typedef __attribute__((ext_vector_type(8))) _Float16 f16x8;
typedef __attribute__((ext_vector_type(2))) _Float16 h2;

static __device__ __forceinline__ unsigned swz(unsigned r) {
  return (r ^ (r >> 3)) & 7u;
}

// fused counted-waitcnt + barrier (single asm: compiler can't reorder across)
#define WB(N) asm volatile("s_waitcnt vmcnt(" #N ")\n\ts_barrier" ::: "memory")

// ---------- prepass 1: x fp32 -> fp16 linear (exact; x was originally fp16) ----------
__global__ __launch_bounds__(256)
void conv_x(const float* __restrict__ X, unsigned short* __restrict__ XH) {
  const size_t i = ((size_t)blockIdx.x * 256 + threadIdx.x) * 8;
  const float4 a = *(const float4*)(X + i);
  const float4 b = *(const float4*)(X + i + 4);
  uint4 o;
  o.x = __builtin_bit_cast(unsigned, __builtin_amdgcn_cvt_pkrtz(a.x, a.y));
  o.y = __builtin_bit_cast(unsigned, __builtin_amdgcn_cvt_pkrtz(a.z, a.w));
  o.z = __builtin_bit_cast(unsigned, __builtin_amdgcn_cvt_pkrtz(b.x, b.y));
  o.w = __builtin_bit_cast(unsigned, __builtin_amdgcn_cvt_pkrtz(b.z, b.w));
  *(uint4*)(XH + i) = o;
}

// ---------- prepass 2: repack qweight nibbles K-major per column ----------
__global__ __launch_bounds__(256)
void repack_qw(const int* __restrict__ QW, unsigned* __restrict__ QWR) {
  const int idx = blockIdx.x * 256 + threadIdx.x;
  const int p  = idx % NPACK;
  const int k8 = idx / NPACK;
  unsigned a[8];
  #pragma unroll
  for (int i = 0; i < 8; ++i)
    a[i] = (unsigned)QW[(size_t)(k8 * 8 + i) * NPACK + p];
  #pragma unroll
  for (int i = 0; i < 8; i += 2) {
    unsigned t = ((a[i] >> 4) ^ a[i + 1]) & 0x0F0F0F0Fu;
    a[i + 1] ^= t;  a[i] ^= t << 4;
  }
  #pragma unroll
  for (int g = 0; g < 8; g += 4)
    #pragma unroll
    for (int i = 0; i < 2; ++i) {
      unsigned t = ((a[g + i] >> 8) ^ a[g + i + 2]) & 0x00FF00FFu;
      a[g + i + 2] ^= t;  a[g + i] ^= t << 8;
    }
  #pragma unroll
  for (int i = 0; i < 4; ++i) {
    unsigned t = ((a[i] >> 16) ^ a[i + 4]) & 0x0000FFFFu;
    a[i + 4] ^= t;  a[i] ^= t << 16;
  }
  const int REV[8] = {0, 4, 1, 5, 2, 6, 3, 7};
  #pragma unroll
  for (int j = 0; j < 8; ++j)
    QWR[(size_t)k8 * N_DIM + 8 * p + j] = a[REV[j]];
}

// ---------- main: 256 thr / 4 waves, per-wave 128x32 (mf=4), counted vmcnt ----------
__global__ __launch_bounds__(256, 2)
void awq_gemm_v4(const unsigned short* __restrict__ XH,
                 const unsigned* __restrict__ QWR,
                 const int* __restrict__ QZ,
                 const float* __restrict__ S,
                 const float* __restrict__ BIAS,
                 float* __restrict__ OUT)
{
  __shared__ unsigned short Abuf0[ATILE];
  __shared__ unsigned short Abuf1[ATILE];

  const int tid  = threadIdx.x;
  const int lane = tid & 63;
  const int wid  = tid >> 6;      // 0..3 = wave column
  const int l31  = lane & 31;
  const int hi   = lane >> 5;

  const int row0 = blockIdx.y * BM;
  const int n0   = blockIdx.x * BN;
  const int col  = n0 + wid * 32 + l31;

  const int jz   = col & 7;
  const int sh_z = (((jz >> 1) | ((jz & 1) << 2)) << 2);

  // ---- hoisted stage pointers: granule g = i*256+tid ----
  const unsigned short* bptr[4];
  #pragma unroll
  for (int i = 0; i < 4; ++i) {
    const int g = i * 256 + tid;
    const unsigned r = (unsigned)(g >> 3), c = (unsigned)(g & 7);
    bptr[i] = XH + (size_t)(row0 + r) * K_DIM + ((c ^ swz(r)) << 3);
  }

  // ---- hoisted A-frag LDS byte offsets: rows mf*32+l31, k8-in-tile ks*2+hi ----
  unsigned aoff[4][4];
  #pragma unroll
  for (int mf = 0; mf < 4; ++mf) {
    const unsigned r = (unsigned)(mf * 32 + l31);
    #pragma unroll
    for (int ks = 0; ks < 4; ++ks)
      aoff[mf][ks] = r * 128 + (((unsigned)(ks * 2 + hi) ^ swz(r)) << 4);
  }

  // ---- hoisted B pointers ----
  const unsigned* pb[4];
  #pragma unroll
  for (int ks = 0; ks < 4; ++ks)
    pb[ks] = QWR + (size_t)(ks * 2 + hi) * N_DIM + col;

  f32x16 acc0 = (f32x16)(0.f), acc1 = (f32x16)(0.f);
  f32x16 acc2 = (f32x16)(0.f), acc3 = (f32x16)(0.f);

  unsigned zz, ss;
  unsigned qn; float sn;
  unsigned bqA[4], bqB[4];

  auto stageA = [&](unsigned short* buf) {           // 4 glds, then bump by BK
    #pragma unroll
    for (int i = 0; i < 4; ++i) {
      __builtin_amdgcn_global_load_lds(
          (const __attribute__((address_space(1))) void*)bptr[i],
          (__attribute__((address_space(3))) void*)(buf + i * 2048 + wid * 512),
          16, 0, 0);
      bptr[i] += BK;
    }
  };
  auto loadB = [&](unsigned* dst) {                  // 4 loads, then bump 1 tile
    #pragma unroll
    for (int ks = 0; ks < 4; ++ks) {
      dst[ks] = *pb[ks];
      pb[ks] += (size_t)8 * N_DIM;
    }
  };
  auto prepLoad = [&](int grp) {
    qn = (unsigned)QZ[grp * NPACK + (col >> 3)];
    sn = S[(size_t)grp * N_DIM + col];
  };
  auto prepCalc = [&]() {
    const unsigned z = (qn >> sh_z) & 15u;
    zz = z * 0x10001u + 0x64006400u;
    ss = __builtin_bit_cast(unsigned, __builtin_amdgcn_cvt_pkrtz(sn, sn));
  };

  auto compute = [&](const unsigned short* Ab, const unsigned* bq) {
    #pragma unroll
    for (int ks = 0; ks < 4; ++ks) {
      const unsigned w = bq[ks];
      const unsigned e = w & 0x0F0F0F0Fu;
      const unsigned o = (w >> 4) & 0x0F0F0F0Fu;
      union { unsigned u[4]; f16x8 v; } bf;
      #pragma unroll
      for (int q = 0; q < 4; ++q) {
        const unsigned sel = 0x0C000C00u | (unsigned)q | ((unsigned)(4 + q) << 16);
        const unsigned hv  = __builtin_amdgcn_perm(o, e, sel) | 0x64006400u;
        const h2 wv = (__builtin_bit_cast(h2, hv) - __builtin_bit_cast(h2, zz)) *
                      __builtin_bit_cast(h2, ss);
        bf.u[q] = __builtin_bit_cast(unsigned, wv);
      }
      acc0 = __builtin_amdgcn_mfma_f32_32x32x16_f16(
          *(const f16x8*)((const char*)Ab + aoff[0][ks]), bf.v, acc0, 0, 0, 0);
      acc1 = __builtin_amdgcn_mfma_f32_32x32x16_f16(
          *(const f16x8*)((const char*)Ab + aoff[1][ks]), bf.v, acc1, 0, 0, 0);
      acc2 = __builtin_amdgcn_mfma_f32_32x32x16_f16(
          *(const f16x8*)((const char*)Ab + aoff[2][ks]), bf.v, acc2, 0, 0, 0);
      acc3 = __builtin_amdgcn_mfma_f32_32x32x16_f16(
          *(const f16x8*)((const char*)Ab + aoff[3][ks]), bf.v, acc3, 0, 0, 0);
    }
  };

  // ---------------- prologue ----------------
  prepLoad(0);       // 2 loads
  stageA(Abuf0);     // 4 glds (tile 0)
  loadB(bqA);        // 4 loads (tile 0)
  loadB(bqB);        // 4 loads (tile 1)
  WB(4);             // drain prep0 + A0 + B0; keep B1 flying

  // ---------------- main loop: I = 0..30, tiles 2I / 2I+1, group I ----------------
  for (int I = 0; I < 31; ++I) {
    // even tile 2I (buf0, bqA)
    prepCalc();                // install group I (loads drained at prev barrier)
    stageA(Abuf1);             // tile 2I+1
    compute(Abuf0, bqA);
    loadB(bqA);                // tile 2I+2
    WB(4);                     // drain B(2I+1) + A(2I+1); keep B(2I+2)

    // odd tile 2I+1 (buf1, bqB)
    stageA(Abuf0);             // tile 2I+2
    compute(Abuf1, bqB);
    loadB(bqB);                // tile 2I+3
    prepLoad(I + 1);           // group I+1
    WB(6);                     // drain B(2I+2) + A(2I+2); keep B(2I+3) + prep
  }

  // ---------------- tail: tiles 62, 63 (group 31) ----------------
  prepCalc();
  stageA(Abuf1);               // tile 63
  compute(Abuf0, bqA);         // tile 62
  WB(0);
  compute(Abuf1, bqB);         // tile 63

  // ---------------- epilogue ----------------
  // C/D 32x32 (m74/m101): col = lane&31, row = (reg&3) + 8*(reg>>2) + 4*(lane>>5)
  const float bz = BIAS[col];
  const f32x16* accs[4] = {&acc0, &acc1, &acc2, &acc3};
  #pragma unroll
  for (int mf = 0; mf < 4; ++mf) {
    const int rbase = row0 + mf * 32 + 4 * hi;
    #pragma unroll
    for (int r = 0; r < 16; ++r) {
      const int row = rbase + (r & 3) + 8 * (r >> 2);
      OUT[(size_t)row * N_DIM + col] = (*accs[mf])[r] + bz;
    }
  }
}

// ---------------- fallback (fp32 x, no/small ws) ----------------
__global__ __launch_bounds__(512, 2)
void awq_gemm_fb(const float* __restrict__ XF,
                 const int* __restrict__ QW,
                 const int* __restrict__ QZ,
                 const float* __restrict__ S,
                 const float* __restrict__ BIAS,
                 float* __restrict__ OUT)
{
  __shared__ unsigned short Al[2][256 * 64];
  __shared__ unsigned short Bl[2][256 * 64];

  const int tid = threadIdx.x, lane = tid & 63, wid = tid >> 6;
  const int wr = wid >> 2, wc = wid & 3, l15 = lane & 15, l4 = lane >> 4;
  const int row0 = blockIdx.y * 256, n0 = blockIdx.x * 256, p0 = n0 >> 3;
  const int dq_p = tid & 31, dq_k = (tid >> 5) << 2;

  f32x4 acc[8][4];
  #pragma unroll
  for (int i = 0; i < 8; ++i)
    #pragma unroll
    for (int j = 0; j < 4; ++j) acc[i][j] = (f32x4){0.f, 0.f, 0.f, 0.f};

  const int SH[8] = {0, 16, 4, 20, 8, 24, 12, 28};
  unsigned zz[8], ssv[8];

  auto stageA = [&](int buf, int k0) {
    #pragma unroll
    for (int i = 0; i < 4; ++i) {
      const int g = i * 512 + tid;
      const unsigned r = (unsigned)(g >> 3), c = (unsigned)(g & 7);
      const float* src = XF + (size_t)(row0 + r) * K_DIM + k0 + (c << 3);
      const float4 v0 = *(const float4*)src;
      const float4 v1 = *(const float4*)(src + 4);
      uint4 o;
      o.x = __builtin_bit_cast(unsigned, __builtin_amdgcn_cvt_pkrtz(v0.x, v0.y));
      o.y = __builtin_bit_cast(unsigned, __builtin_amdgcn_cvt_pkrtz(v0.z, v0.w));
      o.z = __builtin_bit_cast(unsigned, __builtin_amdgcn_cvt_pkrtz(v1.x, v1.y));
      o.w = __builtin_bit_cast(unsigned, __builtin_amdgcn_cvt_pkrtz(v1.z, v1.w));
      *(uint4*)((char*)&Al[buf][0] + r * 128 + ((c ^ swz(r)) << 4)) = o;
    }
  };
  auto prepGroup = [&](int grp) {
    const unsigned qzv = (unsigned)QZ[grp * NPACK + p0 + dq_p];
    const float* sp = S + (size_t)grp * N_DIM + n0 + dq_p * 8;
    const float4 sv0 = *(const float4*)sp;
    const float4 sv1 = *(const float4*)(sp + 4);
    const float svf[8] = {sv0.x, sv0.y, sv0.z, sv0.w, sv1.x, sv1.y, sv1.z, sv1.w};
    #pragma unroll
    for (int j = 0; j < 8; ++j) {
      const unsigned z = (qzv >> SH[j]) & 15u;
      zz[j] = z * 0x10001u + 0x64006400u;
      ssv[j] = __builtin_bit_cast(unsigned, __builtin_amdgcn_cvt_pkrtz(svf[j], svf[j]));
    }
  };
  unsigned qwc[4], qwn[4];
  auto loadQW = [&](unsigned* dst, int k0) {
    #pragma unroll
    for (int i = 0; i < 4; ++i)
      dst[i] = (unsigned)QW[(size_t)(k0 + dq_k + i) * NPACK + p0 + dq_p];
  };
  auto deqB = [&](int buf, const unsigned* qw) {
    #pragma unroll
    for (int j = 0; j < 8; ++j) {
      const int sh = SH[j];
      const unsigned q01 = ((qw[0] >> sh) & 15u) | (((qw[1] >> sh) & 15u) << 16) | 0x64006400u;
      const unsigned q23 = ((qw[2] >> sh) & 15u) | (((qw[3] >> sh) & 15u) << 16) | 0x64006400u;
      const h2 w01 = (__builtin_bit_cast(h2, q01) - __builtin_bit_cast(h2, zz[j])) *
                     __builtin_bit_cast(h2, ssv[j]);
      const h2 w23 = (__builtin_bit_cast(h2, q23) - __builtin_bit_cast(h2, zz[j])) *
                     __builtin_bit_cast(h2, ssv[j]);
      uint2 wb;
      wb.x = __builtin_bit_cast(unsigned, w01);
      wb.y = __builtin_bit_cast(unsigned, w23);
      const unsigned nn = dq_p * 8 + j;
      *(uint2*)((char*)&Bl[buf][0] + nn * 128 + ((dq_k * 2) ^ (swz(nn) << 4))) = wb;
    }
  };

  stageA(0, 0); prepGroup(0); loadQW(qwc, 0); deqB(0, qwc); loadQW(qwn, BK);
  __syncthreads();
  int cur = 0;
  for (int t = 0; t < NT; ++t) {
    if (t + 1 < NT) {
      const int kn = (t + 1) * BK;
      stageA(cur ^ 1, kn);
      if (((t + 1) & 1) == 0) prepGroup((t + 1) >> 1);
      deqB(cur ^ 1, qwn);
      if (t + 2 < NT) loadQW(qwn, kn + BK);
    }
    const char* Ac = (const char*)&Al[cur][0];
    const char* Bc = (const char*)&Bl[cur][0];
    #pragma unroll
    for (int kk = 0; kk < 2; ++kk) {
      f16x8 afv[8], bfv[4];
      #pragma unroll
      for (int m = 0; m < 8; ++m) {
        const unsigned r = (unsigned)(wr * 128 + m * 16 + l15);
        afv[m] = *(const f16x8*)(Ac + r * 128 + (((unsigned)(kk * 4 + l4) ^ swz(r)) << 4));
      }
      #pragma unroll
      for (int n = 0; n < 4; ++n) {
        const unsigned r = (unsigned)(wc * 64 + n * 16 + l15);
        bfv[n] = *(const f16x8*)(Bc + r * 128 + (((unsigned)(kk * 4 + l4) ^ swz(r)) << 4));
      }
      #pragma unroll
      for (int m = 0; m < 8; ++m)
        #pragma unroll
        for (int n = 0; n < 4; ++n)
          acc[m][n] = __builtin_amdgcn_mfma_f32_16x16x32_f16(afv[m], bfv[n], acc[m][n], 0, 0, 0);
    }
    __syncthreads();
    cur ^= 1;
  }
  #pragma unroll
  for (int n = 0; n < 4; ++n) {
    const int c2 = n0 + wc * 64 + n * 16 + l15;
    const float bz = BIAS[c2];
    #pragma unroll
    for (int m = 0; m < 8; ++m) {
      const int rbase = row0 + wr * 128 + m * 16 + l4 * 4;
      #pragma unroll
      for (int r = 0; r < 4; ++r)
        OUT[(size_t)(rbase + r) * N_DIM + c2] = acc[m][n][r] + bz;
    }
  }
}

extern "C" void kernel_launch(void* const* d_in, const int* in_sizes, int n_in,
                              void* d_out, int out_size, void* d_ws, size_t ws_size,
                              hipStream_t stream) {
  const float* x = nullptr; const int* qw = nullptr; const int* qz = nullptr;
  const float* s = nullptr; const float* b = nullptr;
  for (int i = 0; i < n_in; ++i) {
    switch (in_sizes[i]) {
      case M_DIM * K_DIM:   x  = (const float*)d_in[i]; break;
      case K_DIM * NPACK:   qw = (const int*)d_in[i];   break;
      case NGROUPS * NPACK: qz = (const int*)d_in[i];   break;
      case NGROUPS * N_DIM: s  = (const float*)d_in[i]; break;
      case N_DIM:           b  = (const float*)d_in[i]; break;
    }
  }
  float* out = (float*)d_out;

  const size_t xh_bytes  = (size_t)M_DIM * K_DIM * 2;          // 8 MiB
  const size_t qwr_bytes = (size_t)K8 * N_DIM * 4;             // 22.5 MiB
  const int repack_blocks = (NPACK * K8) / 256;                // 2752 exact

  if (ws_size >= xh_bytes + qwr_bytes) {
    unsigned short* xh = (unsigned short*)d_ws;
    unsigned* qwr = (unsigned*)((char*)d_ws + xh_bytes);
    conv_x<<<(M_DIM * K_DIM) / (256 * 8), 256, 0, stream>>>(x, xh);
    repack_qw<<<repack_blocks, 256, 0, stream>>>(qw, qwr);
    awq_gemm_v4<<<dim3(N_DIM / BN, M_DIM / BM), dim3(256), 0, stream>>>(
        xh, qwr, qz, s, b, out);
  } else {
    awq_gemm_fb<<<dim3(N_DIM / 256, M_DIM / 256), dim3(512), 0, stream>>>(
        x, qw, qz, s, b, out);
  }
}